// Round 5
// baseline (398.404 us; speedup 1.0000x reference)
//
#include <hip/hip_runtime.h>
#include <hip/hip_bf16.h>

// EdgePredict: out = softmax((h[u]*h[v]) @ W1 @ W2 @ W3 + biases)
// R0: linear MLP chain collapses to wd[256] + bd; softmax2 = sigmoid(diff).
// R2: f16 table in ws halves gather bytes.
// R4: MFMA dot products, 16 edges/wave-group; VALU 59%->6%.
// Rounds 1-4 invariant: duration tracks 64B LINE REQUESTS (~110 G/s) not
//   bytes/VALU/FETCH. Coalescer merges same-line requests within one
//   instruction -> u-sort the edges so each 16-edge MFMA group shares ~2
//   distinct u rows: u-side requests 8/edge -> ~1/edge. Predicted ~9.5
//   lines/edge -> edge kernel ~82-100 us.

#define D 256

typedef _Float16 half8 __attribute__((ext_vector_type(8)));
typedef float float4v __attribute__((ext_vector_type(4)));

// ---------------------------------------------------------------------------
// prep: zero hist + convert h -> f16 table; block 0 collapses weights.
// ws layout: [0,1152) wc f32 (wd[256], bd at 256); [1280,1792) wdf f16;
//            [2048,...) f16 table 512 B/row; then puv/pidx/hist/cursor/aux.
// ---------------------------------------------------------------------------
__global__ __launch_bounds__(256) void prep(
    const float4* __restrict__ h, half8* __restrict__ tb, int nv8,
    const float* __restrict__ W1, const float* __restrict__ b1,
    const float* __restrict__ W2, const float* __restrict__ b2,
    const float* __restrict__ W3, const float* __restrict__ b3,
    float* __restrict__ wc, _Float16* __restrict__ wdf,
    int* __restrict__ hist, int nhp)
{
    const int gstride = gridDim.x * blockDim.x;
    for (int i = blockIdx.x * blockDim.x + threadIdx.x; i < nhp; i += gstride)
        hist[i] = 0;

    if (blockIdx.x == 0) {
        __shared__ float T[128][2];  // T = W2 @ W3
        const int t = threadIdx.x;
        {
            const int j = t >> 1, c = t & 1;
            float s = 0.f;
            #pragma unroll 8
            for (int k = 0; k < 64; ++k) s += W2[j * 64 + k] * W3[k * 2 + c];
            T[j][c] = s;
        }
        __syncthreads();
        float s0 = 0.f, s1 = 0.f;
        #pragma unroll 8
        for (int j = 0; j < 128; ++j) {
            const float w = W1[t * 128 + j];
            s0 += w * T[j][0];
            s1 += w * T[j][1];
        }
        const float wd = s1 - s0;
        wc[t]  = wd;
        wdf[t] = (_Float16)wd;
        if (t == 0) {
            float f0 = b3[0], f1 = b3[1];
            for (int j = 0; j < 128; ++j) { f0 += b1[j] * T[j][0]; f1 += b1[j] * T[j][1]; }
            for (int k = 0; k < 64; ++k)  { f0 += b2[k] * W3[k * 2 + 0]; f1 += b2[k] * W3[k * 2 + 1]; }
            wc[256] = f1 - f0;  // bd
        }
    }

    for (int i = blockIdx.x * blockDim.x + threadIdx.x; i < nv8; i += gstride) {
        const float4 f0 = h[2 * i];
        const float4 f1 = h[2 * i + 1];
        half8 o;
        o[0] = (_Float16)f0.x; o[1] = (_Float16)f0.y;
        o[2] = (_Float16)f0.z; o[3] = (_Float16)f0.w;
        o[4] = (_Float16)f1.x; o[5] = (_Float16)f1.y;
        o[6] = (_Float16)f1.z; o[7] = (_Float16)f1.w;
        tb[i] = o;
    }
}

// ---------------------------------------------------------------------------
// counting sort by u: hist -> scan(2 kernels) -> scatter (aux folded in)
// ---------------------------------------------------------------------------
__global__ __launch_bounds__(256) void hist_k(
    const int2* __restrict__ edges, int* __restrict__ hist, int E)
{
    const int gstride = gridDim.x * blockDim.x;
    for (int e = blockIdx.x * blockDim.x + threadIdx.x; e < E; e += gstride)
        atomicAdd(&hist[edges[e].x], 1);
}

__global__ __launch_bounds__(256) void scan1(
    const int* __restrict__ in, int* __restrict__ outp, int* __restrict__ aux, int n)
{
    __shared__ int buf[2][256];
    const int t = threadIdx.x;
    const int gid = blockIdx.x * 256 + t;
    const int v = (gid < n) ? in[gid] : 0;
    buf[0][t] = v;
    __syncthreads();
    int src = 0;
    for (int off = 1; off < 256; off <<= 1) {
        int val = buf[src][t];
        if (t >= off) val += buf[src][t - off];
        buf[src ^ 1][t] = val;
        src ^= 1;
        __syncthreads();
    }
    if (gid < n) outp[gid] = buf[src][t] - v;  // block-local exclusive
    if (t == 255) aux[blockIdx.x] = buf[src][t];
}

__global__ __launch_bounds__(256) void scan2(int* __restrict__ aux, int n)
{
    __shared__ int buf[2][256];
    const int t = threadIdx.x;
    int v[4];
    const int base = t * 4;
    for (int k = 0; k < 4; ++k) { const int i = base + k; v[k] = (i < n) ? aux[i] : 0; }
    const int local = v[0] + v[1] + v[2] + v[3];
    buf[0][t] = local;
    __syncthreads();
    int src = 0;
    for (int off = 1; off < 256; off <<= 1) {
        int val = buf[src][t];
        if (t >= off) val += buf[src][t - off];
        buf[src ^ 1][t] = val;
        src ^= 1;
        __syncthreads();
    }
    int run = buf[src][t] - local;
    for (int k = 0; k < 4; ++k) { const int i = base + k; if (i < n) aux[i] = run; run += v[k]; }
}

__global__ __launch_bounds__(256) void scatter_k(
    const int2* __restrict__ edges, int* __restrict__ cursor,
    const int* __restrict__ aux, int2* __restrict__ puv,
    int* __restrict__ pidx, int E)
{
    const int gstride = gridDim.x * blockDim.x;
    for (int e = blockIdx.x * blockDim.x + threadIdx.x; e < E; e += gstride) {
        const int2 ed = edges[e];
        const int pos = atomicAdd(&cursor[ed.x], 1) + aux[ed.x >> 8];
        puv[pos] = ed;
        pidx[pos] = e;
    }
}

// ---------------------------------------------------------------------------
// MFMA edge kernel on u-sorted edges. Each wave owns a contiguous chunk
// (multiple of 16) of the sorted list; a 16-edge group shares ~2 distinct
// u rows -> the coalescer merges the A-side loads to ~2 lines/instruction.
// A[m][k]=tbl[u_m][k]*wd[k] (m=lane&15, k=quad*8+j), B[k][n]=tbl[v_n][k].
// Diagonal of C: lane with quad==(m>>2), reg m&3.
// ---------------------------------------------------------------------------
__global__ __launch_bounds__(256) void edge_mfma_sorted(
    const _Float16* __restrict__ tbl, const int2* __restrict__ puv,
    const int* __restrict__ pidx, const float* __restrict__ wc,
    const _Float16* __restrict__ wdf, float2* __restrict__ out,
    int E, int chunk)
{
    const int lane = threadIdx.x & 63;
    const int m    = lane & 15;
    const int quad = lane >> 4;
    const int wid  = blockIdx.x * (blockDim.x >> 6) + (threadIdx.x >> 6);

    const int s0 = wid * chunk;
    if (s0 >= E) return;
    const int eend = min(E, s0 + chunk);

    const float bd = wc[256];
    const bool diag = (quad == (m >> 2));

    half8 wq[8];
    {
        const half8* wp = (const half8*)(wdf + quad * 8);
        #pragma unroll
        for (int s = 0; s < 8; ++s) wq[s] = wp[4 * s];
    }

    for (int g = s0; g < eend; g += 16) {
        const int em = g + m;
        const bool valid = (em < eend);
        const int ec = valid ? em : (eend - 1);
        const int2 ed = puv[ec];
        const half8* pa = (const half8*)(tbl + (size_t)ed.x * D + quad * 8);
        const half8* pb = (const half8*)(tbl + (size_t)ed.y * D + quad * 8);

        float4v acc = {0.f, 0.f, 0.f, 0.f};
        #pragma unroll
        for (int s = 0; s < 8; ++s) {
            const half8 a = pa[4 * s] * wq[s];
            const half8 b = pb[4 * s];
            acc = __builtin_amdgcn_mfma_f32_16x16x32_f16(a, b, acc, 0, 0, 0);
        }

        if (diag && valid) {
            const float d  = acc[m & 3] + bd;
            const float p1 = 1.0f / (1.0f + __expf(-d));
            out[pidx[em]] = make_float2(1.0f - p1, p1);
        }
    }
}

// ---------------------------------------------------------------------------
// Fallback 1: R4 unsorted MFMA kernel (ws fits table only)
// ---------------------------------------------------------------------------
__global__ __launch_bounds__(256) void edge_mfma(
    const _Float16* __restrict__ tbl, const int2* __restrict__ edges,
    const float* __restrict__ wc, const _Float16* __restrict__ wdf,
    float2* __restrict__ out, int E, int ngroups)
{
    const int lane = threadIdx.x & 63;
    const int m    = lane & 15;
    const int quad = lane >> 4;
    const int wid  = blockIdx.x * (blockDim.x >> 6) + (threadIdx.x >> 6);
    const int nw   = gridDim.x * (blockDim.x >> 6);

    const float bd = wc[256];
    const bool diag = (quad == (m >> 2));

    half8 wq[8];
    {
        const half8* wp = (const half8*)(wdf + quad * 8);
        #pragma unroll
        for (int s = 0; s < 8; ++s) wq[s] = wp[4 * s];
    }

    for (int g = wid; g < ngroups; g += nw) {
        const int em = g * 16 + m;
        const int2 ed = edges[min(em, E - 1)];
        const half8* pa = (const half8*)(tbl + (size_t)ed.x * D + quad * 8);
        const half8* pb = (const half8*)(tbl + (size_t)ed.y * D + quad * 8);

        float4v acc = {0.f, 0.f, 0.f, 0.f};
        #pragma unroll
        for (int s = 0; s < 8; ++s) {
            const half8 a = pa[4 * s] * wq[s];
            const half8 b = pb[4 * s];
            acc = __builtin_amdgcn_mfma_f32_16x16x32_f16(a, b, acc, 0, 0, 0);
        }

        if (diag && em < E) {
            const float d  = acc[m & 3] + bd;
            const float p1 = 1.0f / (1.0f + __expf(-d));
            out[em] = make_float2(1.0f - p1, p1);
        }
    }
}

// ---------------------------------------------------------------------------
// Fallback 2: fp32 gather + wave reduction
// ---------------------------------------------------------------------------
__global__ __launch_bounds__(256) void edge_predict_f32(
    const float* __restrict__ h, const int2* __restrict__ edges,
    const float* __restrict__ wc, float2* __restrict__ out, int E)
{
    const int lane = threadIdx.x & 63;
    const int wid  = blockIdx.x * (blockDim.x >> 6) + (threadIdx.x >> 6);
    const int nw   = gridDim.x * (blockDim.x >> 6);
    const float4 wd = ((const float4*)wc)[lane];
    const float  bd = wc[256];
    for (int e = wid; e < E; e += nw) {
        const int2 ed = edges[e];
        const float4 a = ((const float4*)(h + (size_t)ed.x * D))[lane];
        const float4 b = ((const float4*)(h + (size_t)ed.y * D))[lane];
        float d = a.x * b.x * wd.x + a.y * b.y * wd.y + a.z * b.z * wd.z + a.w * b.w * wd.w;
        #pragma unroll
        for (int mm = 32; mm > 0; mm >>= 1) d += __shfl_xor(d, mm, 64);
        if (lane == 0) {
            const float p1 = 1.0f / (1.0f + __expf(-(d + bd)));
            out[e] = make_float2(1.0f - p1, p1);
        }
    }
}

// ---------------------------------------------------------------------------
extern "C" void kernel_launch(void* const* d_in, const int* in_sizes, int n_in,
                              void* d_out, int out_size, void* d_ws, size_t ws_size,
                              hipStream_t stream)
{
    const float* h     = (const float*)d_in[0];
    const int2*  edges = (const int2*)d_in[1];
    const float* W1    = (const float*)d_in[2];
    const float* b1    = (const float*)d_in[3];
    const float* W2    = (const float*)d_in[4];
    const float* b2    = (const float*)d_in[5];
    const float* W3    = (const float*)d_in[6];
    const float* b3    = (const float*)d_in[7];
    float2* out = (float2*)d_out;

    const int nNodes = in_sizes[0] / D;
    const int E      = in_sizes[1] / 2;
    const int nv8    = nNodes * (D / 8);

    const int    nblk1 = (nNodes + 255) / 256;
    const int    nhp   = nblk1 * 256;

    char* p = (char*)d_ws;
    float*    wc  = (float*)p;
    _Float16* wdf = (_Float16*)(p + 1280);
    _Float16* tbl = (_Float16*)(p + 2048);
    p += 2048 + (size_t)nNodes * D * 2;
    const size_t needTbl = (size_t)(p - (char*)d_ws);
    int2* puv    = (int2*)p;  p += (size_t)E * 8;
    int*  pidx   = (int*)p;   p += (size_t)E * 4;
    int*  hist   = (int*)p;   p += (size_t)nhp * 4;
    int*  cursor = (int*)p;   p += (size_t)nhp * 4;
    int*  aux    = (int*)p;   p += 4096;
    const size_t needSort = (size_t)(p - (char*)d_ws);

    if (ws_size >= needSort && nblk1 <= 1024) {
        prep<<<4096, 256, 0, stream>>>((const float4*)h, (half8*)tbl, nv8,
                                       W1, b1, W2, b2, W3, b3, wc, wdf, hist, nhp);
        hist_k<<<2048, 256, 0, stream>>>(edges, hist, E);
        scan1<<<nblk1, 256, 0, stream>>>(hist, cursor, aux, nNodes);
        scan2<<<1, 256, 0, stream>>>(aux, nblk1);
        scatter_k<<<2048, 256, 0, stream>>>(edges, cursor, aux, puv, pidx, E);
        const int nw = 2048 * 4;
        int chunk = (E + nw - 1) / nw;
        chunk = (chunk + 15) & ~15;  // multiple of 16 keeps groups u-coherent
        edge_mfma_sorted<<<2048, 256, 0, stream>>>(tbl, puv, pidx, wc, wdf,
                                                   out, E, chunk);
    } else if (ws_size >= needTbl) {
        prep<<<4096, 256, 0, stream>>>((const float4*)h, (half8*)tbl, nv8,
                                       W1, b1, W2, b2, W3, b3, wc, wdf, hist, 0);
        const int ngroups = (E + 15) / 16;
        edge_mfma<<<2048, 256, 0, stream>>>(tbl, edges, wc, wdf, out, E, ngroups);
    } else {
        prep<<<1, 256, 0, stream>>>((const float4*)h, (half8*)wc /*unused*/, 0,
                                    W1, b1, W2, b2, W3, b3, wc, wdf, hist, 0);
        edge_predict_f32<<<2048, 256, 0, stream>>>(h, edges, wc, out, E);
    }
}

// Round 6
// 392.794 us; speedup vs baseline: 1.0143x; 1.0143x over previous
//
#include <hip/hip_runtime.h>
#include <hip/hip_bf16.h>

// EdgePredict: out = softmax((h[u]*h[v]) @ W1 @ W2 @ W3 + biases)
// R0: linear MLP chain collapses to wd[256] + bd; softmax2 = sigmoid(diff).
// R2: f16 table in ws halves gather bytes.
// R4: MFMA dot products, 16 edges/wave-group.
// R1-R5 universal invariant: duration = 64B-line requests / ~108 G/s, for
//   EVERY kernel variant (fp32/f16/sorted/mfma). Optimize line count + reorder
//   cost jointly.
// R5 post-mortem: sorted edge kernel hit its floor (10.3 lines/edge, 104 us)
//   but the 5-kernel sort cost 117 us > the 35 us gain.
// R6: bin-by-u in ONE pass (no hist/scan/scatter): 14-slot bins, bin id = u
//   implicit, fill-count masks uninitialized slots, Poisson overflow (~2%)
//   -> spill list processed R4-style in the same kernel. A-side becomes
//   wave-uniform (all C rows equal -> result = acc[0] of quad-0 lane n).

#define D 256
#define NSLOT 14
#define SPILLCAP 32768

typedef _Float16 half8 __attribute__((ext_vector_type(8)));
typedef float float4v __attribute__((ext_vector_type(4)));

// ---------------------------------------------------------------------------
// prep: zero cursors + collapse weights (block 0) + f32 -> f16 table.
// ---------------------------------------------------------------------------
__global__ __launch_bounds__(256) void prep(
    const float4* __restrict__ h, half8* __restrict__ tb, int nv8,
    const float* __restrict__ W1, const float* __restrict__ b1,
    const float* __restrict__ W2, const float* __restrict__ b2,
    const float* __restrict__ W3, const float* __restrict__ b3,
    float* __restrict__ wc, _Float16* __restrict__ wdf,
    int* __restrict__ cursor, int ncur)
{
    const int gstride = gridDim.x * blockDim.x;
    for (int i = blockIdx.x * blockDim.x + threadIdx.x; i < ncur; i += gstride)
        cursor[i] = 0;

    if (blockIdx.x == 0) {
        __shared__ float T[128][2];  // T = W2 @ W3
        const int t = threadIdx.x;
        {
            const int j = t >> 1, c = t & 1;
            float s = 0.f;
            #pragma unroll 8
            for (int k = 0; k < 64; ++k) s += W2[j * 64 + k] * W3[k * 2 + c];
            T[j][c] = s;
        }
        __syncthreads();
        float s0 = 0.f, s1 = 0.f;
        #pragma unroll 8
        for (int j = 0; j < 128; ++j) {
            const float w = W1[t * 128 + j];
            s0 += w * T[j][0];
            s1 += w * T[j][1];
        }
        const float wd = s1 - s0;
        wc[t]  = wd;
        wdf[t] = (_Float16)wd;
        if (t == 0) {
            float f0 = b3[0], f1 = b3[1];
            for (int j = 0; j < 128; ++j) { f0 += b1[j] * T[j][0]; f1 += b1[j] * T[j][1]; }
            for (int k = 0; k < 64; ++k)  { f0 += b2[k] * W3[k * 2 + 0]; f1 += b2[k] * W3[k * 2 + 1]; }
            wc[256] = f1 - f0;  // bd
        }
    }

    for (int i = blockIdx.x * blockDim.x + threadIdx.x; i < nv8; i += gstride) {
        const float4 f0 = h[2 * i];
        const float4 f1 = h[2 * i + 1];
        half8 o;
        o[0] = (_Float16)f0.x; o[1] = (_Float16)f0.y;
        o[2] = (_Float16)f0.z; o[3] = (_Float16)f0.w;
        o[4] = (_Float16)f1.x; o[5] = (_Float16)f1.y;
        o[6] = (_Float16)f1.z; o[7] = (_Float16)f1.w;
        tb[i] = o;
    }
}

// ---------------------------------------------------------------------------
// binfill: single pass. pos<NSLOT -> slot {v, idx}; else spill {u,v,idx}.
// Slots are NOT initialized (0xAA poison) — cursor fill count masks them.
// ---------------------------------------------------------------------------
__global__ __launch_bounds__(256) void binfill(
    const int2* __restrict__ edges, int* __restrict__ cursor,
    int* __restrict__ spillcnt, int2* __restrict__ slots,
    int4* __restrict__ spill, int E)
{
    const int gstride = gridDim.x * blockDim.x;
    for (int e = blockIdx.x * blockDim.x + threadIdx.x; e < E; e += gstride) {
        const int2 ed = edges[e];
        const int pos = atomicAdd(&cursor[ed.x], 1);
        if (pos < NSLOT) {
            slots[(size_t)ed.x * NSLOT + pos] = make_int2(ed.y, e);
        } else {
            const int s = atomicAdd(spillcnt, 1);
            if (s < SPILLCAP) spill[s] = make_int4(ed.x, ed.y, e, 0);
        }
    }
}

// ---------------------------------------------------------------------------
// edge_binned: phase 1 — one bin (node u) per 16-edge MFMA group, 2-bin
// unroll for MLP. A-fragment is wave-uniform (row u for all m) -> every row
// of C equals the result vector: edge n = quad-0 lane n, reg 0.
// phase 2 — spill tail, R4-style per-lane u (verified diag extraction).
// ---------------------------------------------------------------------------
__global__ __launch_bounds__(256) void edge_binned(
    const _Float16* __restrict__ tbl, const int2* __restrict__ slots,
    const int* __restrict__ cursor, const int* __restrict__ spillcnt,
    const int4* __restrict__ spill, const float* __restrict__ wc,
    const _Float16* __restrict__ wdf, float2* __restrict__ out, int NB)
{
    const int lane = threadIdx.x & 63;
    const int m    = lane & 15;
    const int quad = lane >> 4;
    const int wid  = blockIdx.x * (blockDim.x >> 6) + (threadIdx.x >> 6);
    const int nw   = gridDim.x * (blockDim.x >> 6);

    const float bd = wc[256];

    half8 wq[8];
    {
        const half8* wp = (const half8*)(wdf + quad * 8);
        #pragma unroll
        for (int s = 0; s < 8; ++s) wq[s] = wp[4 * s];
    }

    // ---- phase 1: bins, 2 per iteration ----
    for (int b = wid * 2; b < NB; b += nw * 2) {
        const int b2ok = (b + 1 < NB);
        const int bb2  = b2ok ? b + 1 : b;
        const int f1 = min(cursor[b], NSLOT);
        const int f2 = b2ok ? min(cursor[bb2], NSLOT) : 0;
        if ((f1 | f2) == 0) continue;

        const int ms = min(m, NSLOT - 1);
        const int2 r1 = slots[(size_t)b   * NSLOT + ms];
        const int2 r2 = slots[(size_t)bb2 * NSLOT + ms];
        const int v1 = (m < f1) ? r1.x : 0;
        const int v2 = (m < f2) ? r2.x : 0;

        const half8* pa1 = (const half8*)(tbl + (size_t)b   * D + quad * 8);
        const half8* pa2 = (const half8*)(tbl + (size_t)bb2 * D + quad * 8);
        const half8* pb1 = (const half8*)(tbl + (size_t)v1  * D + quad * 8);
        const half8* pb2 = (const half8*)(tbl + (size_t)v2  * D + quad * 8);

        float4v acc1 = {0.f, 0.f, 0.f, 0.f};
        float4v acc2 = {0.f, 0.f, 0.f, 0.f};
        #pragma unroll
        for (int s = 0; s < 8; ++s) {
            acc1 = __builtin_amdgcn_mfma_f32_16x16x32_f16(pa1[4 * s] * wq[s], pb1[4 * s], acc1, 0, 0, 0);
            acc2 = __builtin_amdgcn_mfma_f32_16x16x32_f16(pa2[4 * s] * wq[s], pb2[4 * s], acc2, 0, 0, 0);
        }

        if (quad == 0) {
            if (m < f1) {
                const float p = 1.0f / (1.0f + __expf(-(acc1[0] + bd)));
                out[r1.y] = make_float2(1.0f - p, p);
            }
            if (m < f2) {
                const float p = 1.0f / (1.0f + __expf(-(acc2[0] + bd)));
                out[r2.y] = make_float2(1.0f - p, p);
            }
        }
    }

    // ---- phase 2: spill tail (per-lane u, R4-verified layout) ----
    const int nspill = min(*spillcnt, SPILLCAP);
    if (nspill > 0) {
        const int ngroups = (nspill + 15) >> 4;
        const bool diag = (quad == (m >> 2));
        for (int g = wid; g < ngroups; g += nw) {
            const int i = g * 16 + m;
            const bool valid = (i < nspill);
            const int4 sp = spill[min(i, nspill - 1)];
            const int uu = valid ? sp.x : 0;
            const int vv = valid ? sp.y : 0;
            const half8* pa = (const half8*)(tbl + (size_t)uu * D + quad * 8);
            const half8* pb = (const half8*)(tbl + (size_t)vv * D + quad * 8);
            float4v acc = {0.f, 0.f, 0.f, 0.f};
            #pragma unroll
            for (int s = 0; s < 8; ++s)
                acc = __builtin_amdgcn_mfma_f32_16x16x32_f16(pa[4 * s] * wq[s], pb[4 * s], acc, 0, 0, 0);
            if (diag && valid) {
                const float p = 1.0f / (1.0f + __expf(-(acc[m & 3] + bd)));
                out[sp.z] = make_float2(1.0f - p, p);
            }
        }
    }
}

// ---------------------------------------------------------------------------
// Fallback 1: R4 unsorted MFMA kernel (ws fits table only)
// ---------------------------------------------------------------------------
__global__ __launch_bounds__(256) void edge_mfma(
    const _Float16* __restrict__ tbl, const int2* __restrict__ edges,
    const float* __restrict__ wc, const _Float16* __restrict__ wdf,
    float2* __restrict__ out, int E, int ngroups)
{
    const int lane = threadIdx.x & 63;
    const int m    = lane & 15;
    const int quad = lane >> 4;
    const int wid  = blockIdx.x * (blockDim.x >> 6) + (threadIdx.x >> 6);
    const int nw   = gridDim.x * (blockDim.x >> 6);

    const float bd = wc[256];
    const bool diag = (quad == (m >> 2));

    half8 wq[8];
    {
        const half8* wp = (const half8*)(wdf + quad * 8);
        #pragma unroll
        for (int s = 0; s < 8; ++s) wq[s] = wp[4 * s];
    }

    for (int g = wid; g < ngroups; g += nw) {
        const int em = g * 16 + m;
        const int2 ed = edges[min(em, E - 1)];
        const half8* pa = (const half8*)(tbl + (size_t)ed.x * D + quad * 8);
        const half8* pb = (const half8*)(tbl + (size_t)ed.y * D + quad * 8);

        float4v acc = {0.f, 0.f, 0.f, 0.f};
        #pragma unroll
        for (int s = 0; s < 8; ++s)
            acc = __builtin_amdgcn_mfma_f32_16x16x32_f16(pa[4 * s] * wq[s], pb[4 * s], acc, 0, 0, 0);

        if (diag && em < E) {
            const float p = 1.0f / (1.0f + __expf(-(acc[m & 3] + bd)));
            out[em] = make_float2(1.0f - p, p);
        }
    }
}

// ---------------------------------------------------------------------------
// Fallback 2: fp32 gather + wave reduction
// ---------------------------------------------------------------------------
__global__ __launch_bounds__(256) void edge_predict_f32(
    const float* __restrict__ h, const int2* __restrict__ edges,
    const float* __restrict__ wc, float2* __restrict__ out, int E)
{
    const int lane = threadIdx.x & 63;
    const int wid  = blockIdx.x * (blockDim.x >> 6) + (threadIdx.x >> 6);
    const int nw   = gridDim.x * (blockDim.x >> 6);
    const float4 wd = ((const float4*)wc)[lane];
    const float  bd = wc[256];
    for (int e = wid; e < E; e += nw) {
        const int2 ed = edges[e];
        const float4 a = ((const float4*)(h + (size_t)ed.x * D))[lane];
        const float4 b = ((const float4*)(h + (size_t)ed.y * D))[lane];
        float d = a.x * b.x * wd.x + a.y * b.y * wd.y + a.z * b.z * wd.z + a.w * b.w * wd.w;
        #pragma unroll
        for (int mm = 32; mm > 0; mm >>= 1) d += __shfl_xor(d, mm, 64);
        if (lane == 0) {
            const float p1 = 1.0f / (1.0f + __expf(-(d + bd)));
            out[e] = make_float2(1.0f - p1, p1);
        }
    }
}

// ---------------------------------------------------------------------------
extern "C" void kernel_launch(void* const* d_in, const int* in_sizes, int n_in,
                              void* d_out, int out_size, void* d_ws, size_t ws_size,
                              hipStream_t stream)
{
    const float* h     = (const float*)d_in[0];
    const int2*  edges = (const int2*)d_in[1];
    const float* W1    = (const float*)d_in[2];
    const float* b1    = (const float*)d_in[3];
    const float* W2    = (const float*)d_in[4];
    const float* b2    = (const float*)d_in[5];
    const float* W3    = (const float*)d_in[6];
    const float* b3    = (const float*)d_in[7];
    float2* out = (float2*)d_out;

    const int nNodes = in_sizes[0] / D;
    const int E      = in_sizes[1] / 2;
    const int nv8    = nNodes * (D / 8);

    // ws carve-up (16B-aligned pieces; NSLOT*8=112 keeps slots 16B-aligned)
    char* p = (char*)d_ws;
    float*    wc  = (float*)p;
    _Float16* wdf = (_Float16*)(p + 1280);
    _Float16* tbl = (_Float16*)(p + 2048);
    p += 2048 + (size_t)nNodes * D * 2;
    const size_t needTbl = (size_t)(p - (char*)d_ws);
    int* cursor = (int*)p;
    const int ncur = nNodes + 16;                   // spillcnt lives at [nNodes]
    int* spillcnt = cursor + nNodes;
    p += ((size_t)ncur * 4 + 15) & ~(size_t)15;
    int2* slots = (int2*)p;   p += (size_t)nNodes * NSLOT * 8;
    int4* spill = (int4*)p;   p += (size_t)SPILLCAP * 16;
    const size_t needBin = (size_t)(p - (char*)d_ws);

    if (ws_size >= needBin) {
        prep<<<4096, 256, 0, stream>>>((const float4*)h, (half8*)tbl, nv8,
                                       W1, b1, W2, b2, W3, b3, wc, wdf,
                                       cursor, ncur);
        binfill<<<2048, 256, 0, stream>>>(edges, cursor, spillcnt, slots,
                                          spill, E);
        edge_binned<<<2048, 256, 0, stream>>>(tbl, slots, cursor, spillcnt,
                                              spill, wc, wdf, out, nNodes);
    } else if (ws_size >= needTbl) {
        prep<<<4096, 256, 0, stream>>>((const float4*)h, (half8*)tbl, nv8,
                                       W1, b1, W2, b2, W3, b3, wc, wdf,
                                       cursor, 0);
        const int ngroups = (E + 15) / 16;
        edge_mfma<<<2048, 256, 0, stream>>>(tbl, edges, wc, wdf, out, E, ngroups);
    } else {
        prep<<<1, 256, 0, stream>>>((const float4*)h, (half8*)wc /*unused*/, 0,
                                    W1, b1, W2, b2, W3, b3, wc, wdf,
                                    cursor, 0);
        edge_predict_f32<<<2048, 256, 0, stream>>>(h, edges, wc, out, E);
    }
}

// Round 7
// 313.391 us; speedup vs baseline: 1.2713x; 1.2534x over previous
//
#include <hip/hip_runtime.h>
#include <hip/hip_bf16.h>

// EdgePredict: out = softmax((h[u]*h[v]) @ W1 @ W2 @ W3 + biases)
// R0: linear MLP chain collapses to wd[256] + bd; softmax2 = sigmoid(diff).
// R2: f16 table in ws halves gather bytes.
// R4: MFMA dot products, 16 edges/wave-group -> edge kernel at the 64B-line
//     ceiling (16.25 lines/edge, 117 G lines/s = 7.5 TB/s).
// R5/R6 post-mortem: ANY reorder pass (sort / single-pass binning) costs
//     >=100 us of scattered-line traffic+atomics, but perfect u-ordering only
//     saves 35 us in the edge kernel. Reordering is structurally net-negative.
//     -> revert to the R4 two-dispatch path.
// R7: prep tuning only: nontemporal loads of single-use fp32 h (also keeps
//     the f16 table L3-resident for the gather), nt table stores, grid 8192.

#define D 256

typedef _Float16 half8 __attribute__((ext_vector_type(8)));
typedef float float4v __attribute__((ext_vector_type(4)));

// ---------------------------------------------------------------------------
// prep: collapse weights (block 0) + f32 -> f16 table (nt streaming).
// ws layout: [0,1152) wc f32 (wd[256], bd at 256); [1280,1792) wdf f16;
//            [2048,...) f16 table, 512 B/row.
// ---------------------------------------------------------------------------
__global__ __launch_bounds__(256) void prep(
    const float4v* __restrict__ h, half8* __restrict__ tb, int nv8,
    const float* __restrict__ W1, const float* __restrict__ b1,
    const float* __restrict__ W2, const float* __restrict__ b2,
    const float* __restrict__ W3, const float* __restrict__ b3,
    float* __restrict__ wc, _Float16* __restrict__ wdf)
{
    if (blockIdx.x == 0) {
        __shared__ float T[128][2];  // T = W2 @ W3
        const int t = threadIdx.x;
        {
            const int j = t >> 1, c = t & 1;
            float s = 0.f;
            #pragma unroll 8
            for (int k = 0; k < 64; ++k) s += W2[j * 64 + k] * W3[k * 2 + c];
            T[j][c] = s;
        }
        __syncthreads();
        float s0 = 0.f, s1 = 0.f;
        #pragma unroll 8
        for (int j = 0; j < 128; ++j) {
            const float w = W1[t * 128 + j];
            s0 += w * T[j][0];
            s1 += w * T[j][1];
        }
        const float wd = s1 - s0;
        wc[t]  = wd;
        wdf[t] = (_Float16)wd;
        if (t == 0) {
            float f0 = b3[0], f1 = b3[1];
            for (int j = 0; j < 128; ++j) { f0 += b1[j] * T[j][0]; f1 += b1[j] * T[j][1]; }
            for (int k = 0; k < 64; ++k)  { f0 += b2[k] * W3[k * 2 + 0]; f1 += b2[k] * W3[k * 2 + 1]; }
            wc[256] = f1 - f0;  // bd
        }
    }

    const int gstride = gridDim.x * blockDim.x;
    for (int i = blockIdx.x * blockDim.x + threadIdx.x; i < nv8; i += gstride) {
        const float4v f0 = __builtin_nontemporal_load(&h[2 * i]);
        const float4v f1 = __builtin_nontemporal_load(&h[2 * i + 1]);
        half8 o;
        o[0] = (_Float16)f0.x; o[1] = (_Float16)f0.y;
        o[2] = (_Float16)f0.z; o[3] = (_Float16)f0.w;
        o[4] = (_Float16)f1.x; o[5] = (_Float16)f1.y;
        o[6] = (_Float16)f1.z; o[7] = (_Float16)f1.w;
        __builtin_nontemporal_store(o, &tb[i]);
    }
}

// ---------------------------------------------------------------------------
// MFMA edge kernel (R4, measured at the line-request ceiling):
// 16 edges per wave-group. A[m][k] = tbl[u_m][k]*wd[k] (m=lane&15,
// k=quad*8+j), B[k][n] = tbl[v_n][k]. Logit-diffs = diag(C): lane with
// quad==(m>>2), reg m&3.
// ---------------------------------------------------------------------------
__global__ __launch_bounds__(256) void edge_mfma(
    const _Float16* __restrict__ tbl, const int2* __restrict__ edges,
    const float* __restrict__ wc, const _Float16* __restrict__ wdf,
    float2* __restrict__ out, int E, int ngroups)
{
    const int lane = threadIdx.x & 63;
    const int m    = lane & 15;
    const int quad = lane >> 4;
    const int wid  = blockIdx.x * (blockDim.x >> 6) + (threadIdx.x >> 6);
    const int nw   = gridDim.x * (blockDim.x >> 6);

    const float bd = wc[256];
    const bool diag = (quad == (m >> 2));

    // loop-invariant wd fragments (32 VGPRs)
    half8 wq[8];
    {
        const half8* wp = (const half8*)(wdf + quad * 8);
        #pragma unroll
        for (int s = 0; s < 8; ++s) wq[s] = wp[4 * s];
    }

    for (int g = wid; g < ngroups; g += nw) {
        const int em = g * 16 + m;
        const int2 ed = edges[min(em, E - 1)];
        const half8* pa = (const half8*)(tbl + (size_t)ed.x * D + quad * 8);
        const half8* pb = (const half8*)(tbl + (size_t)ed.y * D + quad * 8);

        float4v acc = {0.f, 0.f, 0.f, 0.f};
        #pragma unroll
        for (int s = 0; s < 8; ++s) {
            const half8 a = pa[4 * s] * wq[s];   // 4x v_pk_mul_f16
            const half8 b = pb[4 * s];
            acc = __builtin_amdgcn_mfma_f32_16x16x32_f16(a, b, acc, 0, 0, 0);
        }

        if (diag && em < E) {
            const float d  = acc[m & 3] + bd;
            const float p1 = 1.0f / (1.0f + __expf(-d));
            out[em] = make_float2(1.0f - p1, p1);
        }
    }
}

// ---------------------------------------------------------------------------
// Fallback: fp32 gather + wave reduction (ws too small for the table)
// ---------------------------------------------------------------------------
__global__ __launch_bounds__(256) void edge_predict_f32(
    const float* __restrict__ h, const int2* __restrict__ edges,
    const float* __restrict__ wc, float2* __restrict__ out, int E)
{
    const int lane = threadIdx.x & 63;
    const int wid  = blockIdx.x * (blockDim.x >> 6) + (threadIdx.x >> 6);
    const int nw   = gridDim.x * (blockDim.x >> 6);
    const float4 wd = ((const float4*)wc)[lane];
    const float  bd = wc[256];
    for (int e = wid; e < E; e += nw) {
        const int2 ed = edges[e];
        const float4 a = ((const float4*)(h + (size_t)ed.x * D))[lane];
        const float4 b = ((const float4*)(h + (size_t)ed.y * D))[lane];
        float d = a.x * b.x * wd.x + a.y * b.y * wd.y + a.z * b.z * wd.z + a.w * b.w * wd.w;
        #pragma unroll
        for (int mm = 32; mm > 0; mm >>= 1) d += __shfl_xor(d, mm, 64);
        if (lane == 0) {
            const float p1 = 1.0f / (1.0f + __expf(-(d + bd)));
            out[e] = make_float2(1.0f - p1, p1);
        }
    }
}

// ---------------------------------------------------------------------------
extern "C" void kernel_launch(void* const* d_in, const int* in_sizes, int n_in,
                              void* d_out, int out_size, void* d_ws, size_t ws_size,
                              hipStream_t stream)
{
    const float* h     = (const float*)d_in[0];
    const int2*  edges = (const int2*)d_in[1];
    const float* W1    = (const float*)d_in[2];
    const float* b1    = (const float*)d_in[3];
    const float* W2    = (const float*)d_in[4];
    const float* b2    = (const float*)d_in[5];
    const float* W3    = (const float*)d_in[6];
    const float* b3    = (const float*)d_in[7];
    float2* out = (float2*)d_out;

    const int nNodes = in_sizes[0] / D;
    const int E      = in_sizes[1] / 2;
    const int nv8    = nNodes * (D / 8);

    float*     wc  = (float*)d_ws;                       // f32 wd[256] + bd
    _Float16*  wdf = (_Float16*)((char*)d_ws + 1280);    // f16 wd[256]
    _Float16*  tbl = (_Float16*)((char*)d_ws + 2048);    // f16 table
    const size_t need = 2048 + (size_t)nNodes * D * 2;

    if (ws_size >= need) {
        prep<<<8192, 256, 0, stream>>>((const float4v*)h, (half8*)tbl, nv8,
                                       W1, b1, W2, b2, W3, b3, wc, wdf);
        const int ngroups = (E + 15) / 16;
        edge_mfma<<<2048, 256, 0, stream>>>(tbl, edges, wc, wdf, out, E, ngroups);
    } else {
        prep<<<1, 256, 0, stream>>>((const float4v*)h, (half8*)wc /*unused*/, 0,
                                    W1, b1, W2, b2, W3, b3, wc, wdf);
        edge_predict_f32<<<2048, 256, 0, stream>>>(h, edges, wc, out, E);
    }
}